// Round 5
// baseline (250.765 us; speedup 1.0000x reference)
//
#include <hip/hip_runtime.h>
#include <stdint.h>

using bf16x8 = __attribute__((ext_vector_type(8))) __bf16;
using f32x4  = __attribute__((ext_vector_type(4))) float;
using u16x8  = __attribute__((ext_vector_type(8))) uint16_t;

#define S_LEN 4096
#define E_DIM 2048
#define D_DIM 128
#define H_NUM 16
#define G_NUM 4
#define QKV_N 3072
#define SCALE 0.08838834764831845f

__device__ inline float bf2f(uint16_t b) {
  union { uint32_t u; float f; } v; v.u = ((uint32_t)b) << 16; return v.f;
}
__device__ inline uint16_t f2bf(float f) {
  union { float f; uint32_t u; } v; v.f = f;
  uint32_t u = v.u + 0x7FFFu + ((v.u >> 16) & 1u);
  return (uint16_t)(u >> 16);
}
__device__ inline uint32_t packbf(float a, float b) {  // (lo=a, hi=b) round-half-up
  union { float f; uint32_t u; } x, y; x.f = a; y.f = b;
  return ((x.u + 0x8000u) >> 16) | ((y.u + 0x8000u) & 0xFFFF0000u);
}
__device__ inline void gload_lds16(const void* g, void* l) {
  __builtin_amdgcn_global_load_lds((const __attribute__((address_space(1))) void*)g,
                                   (__attribute__((address_space(3))) void*)l, 16, 0, 0);
}

// ---------------- fp32 -> bf16 convert (8 elems/thread) ----------------
__global__ __launch_bounds__(256) void conv_f2b(const float* __restrict__ in,
                                                uint16_t* __restrict__ out) {
  const size_t i = ((size_t)blockIdx.x * 256 + threadIdx.x) * 8;
  float4 a = *(const float4*)(in + i);
  float4 b = *(const float4*)(in + i + 4);
  u16x8 o;
  o[0] = f2bf(a.x); o[1] = f2bf(a.y); o[2] = f2bf(a.z); o[3] = f2bf(a.w);
  o[4] = f2bf(b.x); o[5] = f2bf(b.y); o[6] = f2bf(b.z); o[7] = f2bf(b.w);
  *(u16x8*)(out + i) = o;
}

// ---------------- transpose fp32 -> bf16: out[c][r] = bf16(in[r][c]) ----------------
__global__ __launch_bounds__(256) void transpose_f2b(
    const float* __restrict__ in, uint16_t* __restrict__ out,
    int ldi, int ldo)
{
  __shared__ __align__(16) uint16_t tile[64][65];
  const int c0 = blockIdx.x * 64, r0 = blockIdx.y * 64;
  const int t = threadIdx.x;
#pragma unroll
  for (int i = 0; i < 16; ++i) {
    int idx = t + i * 256;
    int r = idx >> 6, c = idx & 63;
    tile[r][c] = f2bf(in[(size_t)(r0 + r) * ldi + c0 + c]);
  }
  __syncthreads();
#pragma unroll
  for (int i = 0; i < 16; ++i) {
    int idx = t + i * 256;
    int cc = idx >> 6, rr = idx & 63;
    out[(size_t)(c0 + cc) * ldo + r0 + rr] = tile[rr][cc];
  }
}

// ---------------- transpose bf16 -> bf16 (for V) ----------------
__global__ __launch_bounds__(256) void transpose_bf16(
    const uint16_t* __restrict__ in, uint16_t* __restrict__ out,
    int ldi, int ldo)
{
  __shared__ __align__(16) uint16_t tile[64][65];
  const int c0 = blockIdx.x * 64, r0 = blockIdx.y * 64;
  const int t = threadIdx.x;
#pragma unroll
  for (int i = 0; i < 16; ++i) {
    int idx = t + i * 256;
    int r = idx >> 6, c = idx & 63;
    tile[r][c] = in[(size_t)(r0 + r) * ldi + c0 + c];
  }
  __syncthreads();
#pragma unroll
  for (int i = 0; i < 16; ++i) {
    int idx = t + i * 256;
    int cc = idx >> 6, rr = idx & 63;
    out[(size_t)(c0 + cc) * ldo + r0 + rr] = tile[rr][cc];
  }
}

// ---------------- GEMM: C = A[M][K](bf16) * Bt[N][K]^T(bf16), f32 acc ----------------
// 1D grid with XCD-aware swizzle (requires gridDim.x % 8 == 0).
__global__ __launch_bounds__(256) void gemm_bt(
    const uint16_t* __restrict__ A, const uint16_t* __restrict__ Bt,
    uint16_t* __restrict__ Cb, float* __restrict__ Cf, int M, int N, int K, int nwgm)
{
  __shared__ __align__(16) uint16_t sA[128 * 32];
  __shared__ __align__(16) uint16_t sB[128 * 32];
  const int nwg = gridDim.x;
  const int id = (blockIdx.x & 7) * (nwg >> 3) + (blockIdx.x >> 3);  // XCD swizzle
  const int m0 = (id % nwgm) * 128, n0 = (id / nwgm) * 128;
  const int tid = threadIdx.x, w = tid >> 6, lane = tid & 63;
  const int lr = lane & 15, lq = lane >> 4;
  const int wr = w >> 1, wc = w & 1;

  f32x4 acc[4][4];
#pragma unroll
  for (int i = 0; i < 4; ++i)
#pragma unroll
    for (int j = 0; j < 4; ++j) acc[i][j] = (f32x4){0.f, 0.f, 0.f, 0.f};

  const int nk = K >> 5;
  const int colb = (lane & 3) << 4;           // byte col within 64B row
  const int rbase0 = w * 32 + (lane >> 2);    // staging row for this lane
  const char* gA0 = (const char*)A + ((size_t)(m0 + rbase0) * K) * 2 + colb;
  const char* gA1 = (const char*)A + ((size_t)(m0 + rbase0 + 16) * K) * 2 + colb;
  const char* gB0 = (const char*)Bt + ((size_t)(n0 + rbase0) * K) * 2 + colb;
  const char* gB1 = (const char*)Bt + ((size_t)(n0 + rbase0 + 16) * K) * 2 + colb;
  char* lA0 = (char*)sA + (w * 2) * 1024;
  char* lA1 = (char*)sA + (w * 2 + 1) * 1024;
  char* lB0 = (char*)sB + (w * 2) * 1024;
  char* lB1 = (char*)sB + (w * 2 + 1) * 1024;

  for (int kt = 0; kt < nk; ++kt) {
    __syncthreads();
    const size_t ko = (size_t)kt * 64;  // 32 elems * 2B
    gload_lds16(gA0 + ko, lA0);
    gload_lds16(gA1 + ko, lA1);
    gload_lds16(gB0 + ko, lB0);
    gload_lds16(gB1 + ko, lB1);
    asm volatile("s_waitcnt vmcnt(0)" ::: "memory");
    __syncthreads();

    bf16x8 af[4], bfj[4];
#pragma unroll
    for (int i = 0; i < 4; ++i) af[i] = *(const bf16x8*)(sA + (wr * 64 + i * 16 + lr) * 32 + lq * 8);
#pragma unroll
    for (int j = 0; j < 4; ++j) bfj[j] = *(const bf16x8*)(sB + (wc * 64 + j * 16 + lr) * 32 + lq * 8);
#pragma unroll
    for (int i = 0; i < 4; ++i)
#pragma unroll
      for (int j = 0; j < 4; ++j)
        acc[i][j] = __builtin_amdgcn_mfma_f32_16x16x32_bf16(af[i], bfj[j], acc[i][j], 0, 0, 0);
  }

  if (Cf) {
#pragma unroll
    for (int i = 0; i < 4; ++i)
#pragma unroll
      for (int j = 0; j < 4; ++j)
#pragma unroll
        for (int r = 0; r < 4; ++r)
          Cf[(size_t)(m0 + wr * 64 + i * 16 + lq * 4 + r) * N + n0 + wc * 64 + j * 16 + lr] =
              acc[i][j][r];
  } else {
#pragma unroll
    for (int i = 0; i < 4; ++i)
#pragma unroll
      for (int j = 0; j < 4; ++j)
#pragma unroll
        for (int r = 0; r < 4; ++r)
          Cb[(size_t)(m0 + wr * 64 + i * 16 + lq * 4 + r) * N + n0 + wc * 64 + j * 16 + lr] =
              f2bf(acc[i][j][r]);
  }
}

// ---------------- RoPE + rearrange for q,k (cos/sin are fp32) ----------------
__global__ __launch_bounds__(256) void rope_qk(
    const uint16_t* __restrict__ qkv, const float* __restrict__ cosb,
    const float* __restrict__ sinb, uint16_t* __restrict__ q_r, uint16_t* __restrict__ k_r)
{
  const int idx = blockIdx.x * 256 + threadIdx.x;  // < 4096*1280
  const int s = idx / 1280;
  const int pp = idx - s * 1280;
  const int c0 = pp << 1;
  const uint32_t xp = *(const uint32_t*)(qkv + (size_t)s * QKV_N + c0);
  const float xe = bf2f((uint16_t)xp), xo = bf2f((uint16_t)(xp >> 16));
  const int dloc = c0 & 127;
  const int dd = dloc >> 1;
  const float cf = cosb[s * 64 + dd];
  const float sf = sinb[s * 64 + dd];
  float oe = xe * cf - xo * sf;
  float oo = xe * sf + xo * cf;
  uint16_t* dst;
  if (c0 < E_DIM) {
    oe *= SCALE; oo *= SCALE;                 // fold 1/sqrt(D) into q
    const int h = c0 >> 7;
    dst = q_r + ((size_t)h * S_LEN + s) * D_DIM + dloc;
  } else {
    const int g = (c0 - E_DIM) >> 7;
    dst = k_r + ((size_t)g * S_LEN + s) * D_DIM + dloc;
  }
  *(uint32_t*)dst = (uint32_t)f2bf(oe) | ((uint32_t)f2bf(oo) << 16);
}

// ---------------- flash attention, window [p-1024, p] ----------------
// QBLK=128, 8 waves x 16 rows. Swapped QK^T (St[k][q]) so each lane owns one
// softmax row (q = lane&15): 2-hop reductions, per-lane M/L, and in-register
// P redistribution via ds_bpermute (no sP LDS round-trip).
__global__ __launch_bounds__(512, 4) void attn_kernel(
    const uint16_t* __restrict__ q_r, const uint16_t* __restrict__ k_r,
    const uint16_t* __restrict__ v_t, uint16_t* __restrict__ o_r)
{
  __shared__ __align__(16) uint16_t sK[2][64 * 128];   // [key][d], swizzled
  __shared__ __align__(16) uint16_t sVT[2][128 * 64];  // [d][key], swizzled
  const int h = blockIdx.y, g = h >> 2;
  const int q0 = blockIdx.x * 128;
  const int tid = threadIdx.x, w = tid >> 6, lane = tid & 63;
  const int lr = lane & 15, lq = lane >> 4;
  const int swz = (lr & 7) << 3;  // element-index XOR for swizzled reads

  const int pmin = q0 + w * 16, pmax = pmin + 15;
  const int pq = pmin + lr;       // this lane's softmax row (q index)

  bf16x8 aq[4];  // Q[q=pmin+lr][d=ks*32+lq*8+e] — B-fragment for swapped QK^T
  {
    const uint16_t* qb = q_r + ((size_t)h * S_LEN + pmin + lr) * D_DIM + lq * 8;
#pragma unroll
    for (int ks = 0; ks < 4; ++ks) aq[ks] = *(const bf16x8*)(qb + ks * 32);
  }
  f32x4 accO[8];
#pragma unroll
  for (int dt = 0; dt < 8; ++dt) accO[dt] = (f32x4){0.f, 0.f, 0.f, 0.f};
  float M = -1e30f, L = 0.f;

  const int jstart = (q0 >= 1024) ? (q0 - 1024) : 0;
  const int nt = (q0 + 128 - jstart) >> 6;
  const char* kb = (const char*)(k_r + ((size_t)g * S_LEN + jstart) * D_DIM);
  const char* vb = (const char*)(v_t + (size_t)g * D_DIM * S_LEN + jstart);

  // per-lane staging geometry (pre-swizzled global sources; 2 chunks/wave each)
  const int kc_row = lane >> 4;                         // row within 4-row K chunk
  const int k_col0 = (lane & 15) << 4;                  // linear byte col (K)
  const int v_scol = (((lane & 7) ^ (lane >> 3)) << 4); // swizzled byte col (V)
  const int v_row = lane >> 3;                          // row within 8-row V chunk

#define STAGE_KV(buf, tt)                                                              \
  {                                                                                    \
    const char* kt_ = kb + (size_t)(tt) * 16384;                                       \
    const char* vt_ = vb + (size_t)(tt) * 128;                                         \
    _Pragma("unroll")                                                                  \
    for (int it = 0; it < 2; ++it) {                                                   \
      const int c = w * 2 + it;                                                        \
      const int krow = c * 4 + kc_row;                                                 \
      const int kscol = k_col0 ^ ((krow & 7) << 4);                                    \
      gload_lds16(kt_ + krow * 256 + kscol, (char*)sK[buf] + c * 1024 + lane * 16);    \
      const int vrow = c * 8 + v_row;                                                  \
      gload_lds16(vt_ + (size_t)vrow * (S_LEN * 2) + v_scol,                           \
                  (char*)sVT[buf] + c * 1024 + lane * 16);                             \
    }                                                                                  \
  }

  STAGE_KV(0, 0)
  asm volatile("s_waitcnt vmcnt(0)" ::: "memory");
  __syncthreads();

  // P-redistribution lane constants
  const int srcA = (lane & 15) | ((lane & 16) << 1);  // lr + 32*(lq&1)
  const int srcB = srcA + 16;
  const bool hs = (lane & 32) != 0;                   // lq>>1

  for (int t = 0; t < nt; ++t) {
    const int b = t & 1;
    if (t + 1 < nt) STAGE_KV(b ^ 1, t + 1)
    const int j0 = jstart + t * 64;
    const uint16_t* Kb = sK[b];
    const uint16_t* Vb = sVT[b];

    // wave-level tile skip: fully outside [pmin-1024, pmax]?
    const bool active = (j0 <= pmax) && (j0 + 63 + 1024 >= pmin);
    if (active) {
      // swapped QK^T: St[k][q]; accS[ct] holds k = ct*16 + lq*4 + r, q = lr
      f32x4 accS[4];
      __builtin_amdgcn_s_setprio(1);
#pragma unroll
      for (int ct = 0; ct < 4; ++ct) {
        accS[ct] = (f32x4){0.f, 0.f, 0.f, 0.f};
#pragma unroll
        for (int ks = 0; ks < 4; ++ks) {
          bf16x8 bk = *(const bf16x8*)(Kb + (ct * 16 + lr) * 128 + ((ks * 32 + lq * 8) ^ swz));
          accS[ct] = __builtin_amdgcn_mfma_f32_16x16x32_bf16(bk, aq[ks], accS[ct], 0, 0, 0);
        }
      }
      __builtin_amdgcn_s_setprio(0);

      // mask only edge tiles (wave-uniform branch); j = key index of accS[ct][r]
      const bool need_mask = (j0 + 63 > pmin) || (j0 < pmax - 1024);
      if (need_mask) {
#pragma unroll
        for (int ct = 0; ct < 4; ++ct) {
#pragma unroll
          for (int r = 0; r < 4; ++r) {
            const int j = j0 + ct * 16 + lq * 4 + r;
            const bool ok = (j <= pq) && (j + 1024 >= pq);
            accS[ct][r] = ok ? accS[ct][r] : -1e30f;
          }
        }
      }

      // row max: 15 local fmax + 2 shfl hops (row q=lr spread over 4 lq-groups)
      float mx = accS[0][0];
#pragma unroll
      for (int ct = 0; ct < 4; ++ct)
#pragma unroll
        for (int r = 0; r < 4; ++r) mx = fmaxf(mx, accS[ct][r]);
      mx = fmaxf(mx, __shfl_xor(mx, 16));
      mx = fmaxf(mx, __shfl_xor(mx, 32));

      // exact defer-rescale
      if (__any(mx > M)) {
        const float Mn = fmaxf(M, mx);
        const float al = __expf(M - Mn);
        M = Mn;
        L *= al;
        float alq[4];
#pragma unroll
        for (int r = 0; r < 4; ++r) alq[r] = __shfl(al, lq * 4 + r);
#pragma unroll
        for (int dt = 0; dt < 8; ++dt)
#pragma unroll
          for (int r = 0; r < 4; ++r) accO[dt][r] *= alq[r];
      }

      // P = exp(S - M), row sum with 2 hops
      float rs = 0.f;
#pragma unroll
      for (int ct = 0; ct < 4; ++ct)
#pragma unroll
        for (int r = 0; r < 4; ++r) {
          const float pv = __expf(accS[ct][r] - M);
          accS[ct][r] = pv;
          rs += pv;
        }
      rs += __shfl_xor(rs, 16);
      rs += __shfl_xor(rs, 32);
      L += rs;

      // pack P pairs lane-locally: wd[ct][i] = bf16x2 of k = ct*16+lq*4+{2i,2i+1}
      uint32_t wd[4][2];
#pragma unroll
      for (int ct = 0; ct < 4; ++ct) {
        wd[ct][0] = packbf(accS[ct][0], accS[ct][1]);
        wd[ct][1] = packbf(accS[ct][2], accS[ct][3]);
      }
      // redistribute: lane needs P[q=lr][k=32js+8lq+e] -> shuffle all 8 words
      // from srcA and srcB, select by hs
      uint32_t sa[4][2], sb[4][2];
#pragma unroll
      for (int c = 0; c < 4; ++c)
#pragma unroll
        for (int i = 0; i < 2; ++i) {
          sa[c][i] = (uint32_t)__shfl((int)wd[c][i], srcA);
          sb[c][i] = (uint32_t)__shfl((int)wd[c][i], srcB);
        }

      __builtin_amdgcn_s_setprio(1);
#pragma unroll
      for (int js = 0; js < 2; ++js) {
        union { uint32_t u[4]; bf16x8 v; } ap;
        ap.u[0] = hs ? sa[js * 2 + 1][0] : sa[js * 2][0];
        ap.u[1] = hs ? sa[js * 2 + 1][1] : sa[js * 2][1];
        ap.u[2] = hs ? sb[js * 2 + 1][0] : sb[js * 2][0];
        ap.u[3] = hs ? sb[js * 2 + 1][1] : sb[js * 2][1];
#pragma unroll
        for (int dt = 0; dt < 8; ++dt) {
          bf16x8 bv = *(const bf16x8*)(Vb + (dt * 16 + lr) * 64 + ((js * 32 + lq * 8) ^ swz));
          accO[dt] = __builtin_amdgcn_mfma_f32_16x16x32_bf16(ap.v, bv, accO[dt], 0, 0, 0);
        }
      }
      __builtin_amdgcn_s_setprio(0);
    }

    asm volatile("s_waitcnt vmcnt(0)" ::: "memory");
    __syncthreads();
  }

  // epilogue: accO row q = lq*4+r, col d = dt*16+lr; 1/L lives at lane lr=q
  const float ivl = 1.f / L;
  float il[4];
#pragma unroll
  for (int r = 0; r < 4; ++r) il[r] = __shfl(ivl, lq * 4 + r);
#pragma unroll
  for (int dt = 0; dt < 8; ++dt)
#pragma unroll
    for (int r = 0; r < 4; ++r) {
      const int p = pmin + lq * 4 + r;
      o_r[(size_t)p * E_DIM + h * D_DIM + dt * 16 + lr] = f2bf(accO[dt][r] * il[r]);
    }
}

extern "C" void kernel_launch(void* const* d_in, const int* in_sizes, int n_in,
                              void* d_out, int out_size, void* d_ws, size_t ws_size,
                              hipStream_t stream) {
  const float* x     = (const float*)d_in[0];
  const float* fcos  = (const float*)d_in[1];
  const float* fsin  = (const float*)d_in[2];
  const float* w_in  = (const float*)d_in[3];
  const float* w_out = (const float*)d_in[4];
  float* out = (float*)d_out;

  char* ws = (char*)d_ws;
  size_t off = 0;
  uint16_t* w_inT  = (uint16_t*)(ws + off); off += (size_t)QKV_N * E_DIM * 2;      // 3072x2048 bf16
  uint16_t* w_outT = (uint16_t*)(ws + off); off += (size_t)E_DIM * E_DIM * 2;      // 2048x2048 bf16
  uint16_t* qkv    = (uint16_t*)(ws + off); off += (size_t)S_LEN * QKV_N * 2;      // 4096x3072 bf16
  uint16_t* q_r    = (uint16_t*)(ws + off); off += (size_t)H_NUM * S_LEN * D_DIM * 2;
  uint16_t* k_r    = (uint16_t*)(ws + off); off += (size_t)G_NUM * S_LEN * D_DIM * 2;
  uint16_t* v_t    = (uint16_t*)(ws + off); off += (size_t)G_NUM * D_DIM * S_LEN * 2;
  uint16_t* o_r    = (uint16_t*)(ws + off); off += (size_t)S_LEN * E_DIM * 2;
  // x_bf aliases o_r: x_bf is consumed by gemm1 before attn writes o_r (stream-ordered).
  uint16_t* x_bf   = o_r;  // 4096x2048 bf16, same size as o_r

  // edge conversions: fp32 -> bf16
  conv_f2b<<<(S_LEN * E_DIM) / (256 * 8), 256, 0, stream>>>(x, x_bf);
  transpose_f2b<<<dim3(QKV_N / 64, E_DIM / 64), 256, 0, stream>>>(w_in, w_inT, QKV_N, E_DIM);
  transpose_f2b<<<dim3(E_DIM / 64, E_DIM / 64), 256, 0, stream>>>(w_out, w_outT, E_DIM, E_DIM);
  // qkv = x @ w_in  (bf16 out); grid flattened, %8==0 for XCD swizzle
  gemm_bt<<<(S_LEN / 128) * (QKV_N / 128), 256, 0, stream>>>(x_bf, w_inT, qkv, nullptr,
                                                             S_LEN, QKV_N, E_DIM, S_LEN / 128);
  // rope q,k ; transpose v
  rope_qk<<<(S_LEN * 1280) / 256, 256, 0, stream>>>(qkv, fcos, fsin, q_r, k_r);
  transpose_bf16<<<dim3(512 / 64, S_LEN / 64), 256, 0, stream>>>(qkv + 2560, v_t, QKV_N, S_LEN);
  // attention (QBLK=128, 8 waves)
  attn_kernel<<<dim3(S_LEN / 128, H_NUM), 512, 0, stream>>>(q_r, k_r, v_t, o_r);
  // out = o @ w_out  (fp32 out)
  gemm_bt<<<(S_LEN / 128) * (E_DIM / 128), 256, 0, stream>>>(o_r, w_outT, nullptr, out,
                                                             S_LEN, E_DIM, E_DIM, S_LEN / 128);
}

// Round 6
// 225.859 us; speedup vs baseline: 1.1103x; 1.1103x over previous
//
#include <hip/hip_runtime.h>
#include <stdint.h>

using bf16x8 = __attribute__((ext_vector_type(8))) __bf16;
using f32x4  = __attribute__((ext_vector_type(4))) float;
using f32x16 = __attribute__((ext_vector_type(16))) float;
using u16x8  = __attribute__((ext_vector_type(8))) uint16_t;

#define S_LEN 4096
#define E_DIM 2048
#define D_DIM 128
#define H_NUM 16
#define G_NUM 4
#define QKV_N 3072
#define SCALE 0.08838834764831845f

__device__ inline float bf2f(uint16_t b) {
  union { uint32_t u; float f; } v; v.u = ((uint32_t)b) << 16; return v.f;
}
__device__ inline uint16_t f2bf(float f) {
  union { float f; uint32_t u; } v; v.f = f;
  uint32_t u = v.u + 0x7FFFu + ((v.u >> 16) & 1u);
  return (uint16_t)(u >> 16);
}
__device__ inline uint32_t packbf(float a, float b) {  // (lo=a, hi=b) round-half-up
  union { float f; uint32_t u; } x, y; x.f = a; y.f = b;
  return ((x.u + 0x8000u) >> 16) | ((y.u + 0x8000u) & 0xFFFF0000u);
}
// in-place half-swap: a' = {a.lo31, b.lo31<-from hi lanes' view}; after:
// lanes<32: a=own a, b=partner a ; lanes>=32: a=partner b, b=own b
__device__ inline void plswap(uint32_t& a, uint32_t& b) {
  asm volatile("v_permlane32_swap_b32 %0, %1" : "+v"(a), "+v"(b));
}
__device__ inline void gload_lds16(const void* g, void* l) {
  __builtin_amdgcn_global_load_lds((const __attribute__((address_space(1))) void*)g,
                                   (__attribute__((address_space(3))) void*)l, 16, 0, 0);
}

// ---------------- fp32 -> bf16 convert (8 elems/thread) ----------------
__global__ __launch_bounds__(256) void conv_f2b(const float* __restrict__ in,
                                                uint16_t* __restrict__ out) {
  const size_t i = ((size_t)blockIdx.x * 256 + threadIdx.x) * 8;
  float4 a = *(const float4*)(in + i);
  float4 b = *(const float4*)(in + i + 4);
  u16x8 o;
  o[0] = f2bf(a.x); o[1] = f2bf(a.y); o[2] = f2bf(a.z); o[3] = f2bf(a.w);
  o[4] = f2bf(b.x); o[5] = f2bf(b.y); o[6] = f2bf(b.z); o[7] = f2bf(b.w);
  *(u16x8*)(out + i) = o;
}

// ---------------- transpose fp32 -> bf16: out[c][r] = bf16(in[r][c]) ----------------
__global__ __launch_bounds__(256) void transpose_f2b(
    const float* __restrict__ in, uint16_t* __restrict__ out,
    int ldi, int ldo)
{
  __shared__ __align__(16) uint16_t tile[64][65];
  const int c0 = blockIdx.x * 64, r0 = blockIdx.y * 64;
  const int t = threadIdx.x;
#pragma unroll
  for (int i = 0; i < 16; ++i) {
    int idx = t + i * 256;
    int r = idx >> 6, c = idx & 63;
    tile[r][c] = f2bf(in[(size_t)(r0 + r) * ldi + c0 + c]);
  }
  __syncthreads();
#pragma unroll
  for (int i = 0; i < 16; ++i) {
    int idx = t + i * 256;
    int cc = idx >> 6, rr = idx & 63;
    out[(size_t)(c0 + cc) * ldo + r0 + rr] = tile[rr][cc];
  }
}

// ---------------- transpose bf16 -> bf16 (for V) ----------------
__global__ __launch_bounds__(256) void transpose_bf16(
    const uint16_t* __restrict__ in, uint16_t* __restrict__ out,
    int ldi, int ldo)
{
  __shared__ __align__(16) uint16_t tile[64][65];
  const int c0 = blockIdx.x * 64, r0 = blockIdx.y * 64;
  const int t = threadIdx.x;
#pragma unroll
  for (int i = 0; i < 16; ++i) {
    int idx = t + i * 256;
    int r = idx >> 6, c = idx & 63;
    tile[r][c] = in[(size_t)(r0 + r) * ldi + c0 + c];
  }
  __syncthreads();
#pragma unroll
  for (int i = 0; i < 16; ++i) {
    int idx = t + i * 256;
    int cc = idx >> 6, rr = idx & 63;
    out[(size_t)(c0 + cc) * ldo + r0 + rr] = tile[rr][cc];
  }
}

// ---------------- GEMM: C = A[M][K](bf16) * Bt[N][K]^T(bf16), f32 acc ----------------
// 1D grid with XCD-aware swizzle (requires gridDim.x % 8 == 0).
__global__ __launch_bounds__(256) void gemm_bt(
    const uint16_t* __restrict__ A, const uint16_t* __restrict__ Bt,
    uint16_t* __restrict__ Cb, float* __restrict__ Cf, int M, int N, int K, int nwgm)
{
  __shared__ __align__(16) uint16_t sA[128 * 32];
  __shared__ __align__(16) uint16_t sB[128 * 32];
  const int nwg = gridDim.x;
  const int id = (blockIdx.x & 7) * (nwg >> 3) + (blockIdx.x >> 3);  // XCD swizzle
  const int m0 = (id % nwgm) * 128, n0 = (id / nwgm) * 128;
  const int tid = threadIdx.x, w = tid >> 6, lane = tid & 63;
  const int lr = lane & 15, lq = lane >> 4;
  const int wr = w >> 1, wc = w & 1;

  f32x4 acc[4][4];
#pragma unroll
  for (int i = 0; i < 4; ++i)
#pragma unroll
    for (int j = 0; j < 4; ++j) acc[i][j] = (f32x4){0.f, 0.f, 0.f, 0.f};

  const int nk = K >> 5;
  const int colb = (lane & 3) << 4;           // byte col within 64B row
  const int rbase0 = w * 32 + (lane >> 2);    // staging row for this lane
  const char* gA0 = (const char*)A + ((size_t)(m0 + rbase0) * K) * 2 + colb;
  const char* gA1 = (const char*)A + ((size_t)(m0 + rbase0 + 16) * K) * 2 + colb;
  const char* gB0 = (const char*)Bt + ((size_t)(n0 + rbase0) * K) * 2 + colb;
  const char* gB1 = (const char*)Bt + ((size_t)(n0 + rbase0 + 16) * K) * 2 + colb;
  char* lA0 = (char*)sA + (w * 2) * 1024;
  char* lA1 = (char*)sA + (w * 2 + 1) * 1024;
  char* lB0 = (char*)sB + (w * 2) * 1024;
  char* lB1 = (char*)sB + (w * 2 + 1) * 1024;

  for (int kt = 0; kt < nk; ++kt) {
    __syncthreads();
    const size_t ko = (size_t)kt * 64;  // 32 elems * 2B
    gload_lds16(gA0 + ko, lA0);
    gload_lds16(gA1 + ko, lA1);
    gload_lds16(gB0 + ko, lB0);
    gload_lds16(gB1 + ko, lB1);
    asm volatile("s_waitcnt vmcnt(0)" ::: "memory");
    __syncthreads();

    bf16x8 af[4], bfj[4];
#pragma unroll
    for (int i = 0; i < 4; ++i) af[i] = *(const bf16x8*)(sA + (wr * 64 + i * 16 + lr) * 32 + lq * 8);
#pragma unroll
    for (int j = 0; j < 4; ++j) bfj[j] = *(const bf16x8*)(sB + (wc * 64 + j * 16 + lr) * 32 + lq * 8);
#pragma unroll
    for (int i = 0; i < 4; ++i)
#pragma unroll
      for (int j = 0; j < 4; ++j)
        acc[i][j] = __builtin_amdgcn_mfma_f32_16x16x32_bf16(af[i], bfj[j], acc[i][j], 0, 0, 0);
  }

  if (Cf) {
#pragma unroll
    for (int i = 0; i < 4; ++i)
#pragma unroll
      for (int j = 0; j < 4; ++j)
#pragma unroll
        for (int r = 0; r < 4; ++r)
          Cf[(size_t)(m0 + wr * 64 + i * 16 + lq * 4 + r) * N + n0 + wc * 64 + j * 16 + lr] =
              acc[i][j][r];
  } else {
#pragma unroll
    for (int i = 0; i < 4; ++i)
#pragma unroll
      for (int j = 0; j < 4; ++j)
#pragma unroll
        for (int r = 0; r < 4; ++r)
          Cb[(size_t)(m0 + wr * 64 + i * 16 + lq * 4 + r) * N + n0 + wc * 64 + j * 16 + lr] =
              f2bf(acc[i][j][r]);
  }
}

// ---------------- RoPE + rearrange for q,k (cos/sin are fp32) ----------------
__global__ __launch_bounds__(256) void rope_qk(
    const uint16_t* __restrict__ qkv, const float* __restrict__ cosb,
    const float* __restrict__ sinb, uint16_t* __restrict__ q_r, uint16_t* __restrict__ k_r)
{
  const int idx = blockIdx.x * 256 + threadIdx.x;  // < 4096*1280
  const int s = idx / 1280;
  const int pp = idx - s * 1280;
  const int c0 = pp << 1;
  const uint32_t xp = *(const uint32_t*)(qkv + (size_t)s * QKV_N + c0);
  const float xe = bf2f((uint16_t)xp), xo = bf2f((uint16_t)(xp >> 16));
  const int dloc = c0 & 127;
  const int dd = dloc >> 1;
  const float cf = cosb[s * 64 + dd];
  const float sf = sinb[s * 64 + dd];
  float oe = xe * cf - xo * sf;
  float oo = xe * sf + xo * cf;
  uint16_t* dst;
  if (c0 < E_DIM) {
    oe *= SCALE; oo *= SCALE;                 // fold 1/sqrt(D) into q
    const int h = c0 >> 7;
    dst = q_r + ((size_t)h * S_LEN + s) * D_DIM + dloc;
  } else {
    const int g = (c0 - E_DIM) >> 7;
    dst = k_r + ((size_t)g * S_LEN + s) * D_DIM + dloc;
  }
  *(uint32_t*)dst = (uint32_t)f2bf(oe) | ((uint32_t)f2bf(oo) << 16);
}

// ---------------- flash attention, window [p-1024, p] ----------------
// 32x32x16 MFMA path: 4 waves x 32 q-rows (QBLK=128). Swapped QK^T puts the
// softmax row on lane&31 (1-hop reduce); P->PV A-frags built in-register via
// cvt-pack + v_permlane32_swap_b32 (zero LDS). 2x FLOP per LDS byte vs 16x16.
__global__ __launch_bounds__(256, 2) void attn_kernel(
    const uint16_t* __restrict__ q_r, const uint16_t* __restrict__ k_r,
    const uint16_t* __restrict__ v_t, uint16_t* __restrict__ o_r)
{
  __shared__ __align__(16) uint16_t sK[2][64 * 128];   // [key][d], swizzled
  __shared__ __align__(16) uint16_t sVT[2][128 * 64];  // [d][key], swizzled
  const int h = blockIdx.y, g = h >> 2;
  const int q0 = blockIdx.x * 128;
  const int tid = threadIdx.x, w = tid >> 6, lane = tid & 63;
  const int lc = lane & 31, hi = lane >> 5;
  const int pmin = q0 + w * 32, pmax = pmin + 31;
  const int pq = pmin + lc;       // this lane's softmax row (q index)

  // Q regs: 8 k-slices of 16; lane holds Q[q=pq][d = ks*16 + hi*8 + e]
  bf16x8 aq[8];
  {
    const uint16_t* qb = q_r + ((size_t)h * S_LEN + pq) * D_DIM + hi * 8;
#pragma unroll
    for (int ks = 0; ks < 8; ++ks) aq[ks] = *(const bf16x8*)(qb + ks * 16);
  }
  f32x16 accO[4];
#pragma unroll
  for (int dt = 0; dt < 4; ++dt) accO[dt] = 0;
  float M = -1e30f, L = 0.f;

  const int jstart = (q0 >= 1024) ? (q0 - 1024) : 0;
  const int nt = (q0 + 128 - jstart) >> 6;
  const char* kb = (const char*)(k_r + ((size_t)g * S_LEN + jstart) * D_DIM);
  const char* vb = (const char*)(v_t + (size_t)g * D_DIM * S_LEN + jstart);

  // per-lane staging geometry (pre-swizzled global sources; 4 chunks/wave)
  const int kc_row = lane >> 4;                         // row within 4-row K chunk
  const int k_col0 = (lane & 15) << 4;                  // linear byte col (K)
  const int v_scol = (((lane & 7) ^ (lane >> 3)) << 4); // swizzled byte col (V)
  const int v_row = lane >> 3;                          // row within 8-row V chunk

#define STAGE_KV(buf, tt)                                                              \
  {                                                                                    \
    const char* kt_ = kb + (size_t)(tt) * 16384;                                       \
    const char* vt_ = vb + (size_t)(tt) * 128;                                         \
    _Pragma("unroll")                                                                  \
    for (int it = 0; it < 4; ++it) {                                                   \
      const int c = w * 4 + it;                                                        \
      const int krow = c * 4 + kc_row;                                                 \
      const int kscol = k_col0 ^ ((krow & 7) << 4);                                    \
      gload_lds16(kt_ + krow * 256 + kscol, (char*)sK[buf] + c * 1024 + lane * 16);    \
      const int vrow = c * 8 + v_row;                                                  \
      gload_lds16(vt_ + (size_t)vrow * (S_LEN * 2) + v_scol,                           \
                  (char*)sVT[buf] + c * 1024 + lane * 16);                             \
    }                                                                                  \
  }

  STAGE_KV(0, 0)
  asm volatile("s_waitcnt vmcnt(0)" ::: "memory");
  __syncthreads();

  for (int t = 0; t < nt; ++t) {
    const int b = t & 1;
    if (t + 1 < nt) STAGE_KV(b ^ 1, t + 1)
    const int j0 = jstart + t * 64;
    const uint16_t* Kb = sK[b];
    const uint16_t* Vb = sVT[b];

    // wave-level tile skip: fully outside [pmin-1024, pmax]?
    const bool active = (j0 <= pmax) && (j0 + 63 + 1024 >= pmin);
    if (active) {
      // swapped QK^T: St[k][q]; accS[rt]: k = rt*32 + (c&3)+8*(c>>2)+4*hi, q = lc
      f32x16 accS[2];
      accS[0] = 0; accS[1] = 0;
      __builtin_amdgcn_s_setprio(1);
#pragma unroll
      for (int rt = 0; rt < 2; ++rt) {
        const int krow = rt * 32 + lc;
        const int ksw = (krow & 7) << 3;
#pragma unroll
        for (int ks = 0; ks < 8; ++ks) {
          bf16x8 ak = *(const bf16x8*)(Kb + krow * 128 + ((ks * 16 + hi * 8) ^ ksw));
          accS[rt] = __builtin_amdgcn_mfma_f32_32x32x16_bf16(ak, aq[ks], accS[rt], 0, 0, 0);
        }
      }
      __builtin_amdgcn_s_setprio(0);

      // mask only edge tiles (wave-uniform branch)
      const bool need_mask = (j0 + 63 > pmin) || (j0 < pmax - 1024);
      if (need_mask) {
#pragma unroll
        for (int rt = 0; rt < 2; ++rt)
#pragma unroll
          for (int c = 0; c < 16; ++c) {
            const int j = j0 + rt * 32 + (c & 3) + 8 * (c >> 2) + 4 * hi;
            const bool ok = (j <= pq) && (j + 1024 >= pq);
            accS[rt][c] = ok ? accS[rt][c] : -1e30f;
          }
      }

      // row max: 31 local fmax + 1 cross-half hop
      float mx = accS[0][0];
#pragma unroll
      for (int rt = 0; rt < 2; ++rt)
#pragma unroll
        for (int c = 0; c < 16; ++c) mx = fmaxf(mx, accS[rt][c]);
      mx = fmaxf(mx, __shfl_xor(mx, 32));

      // deferred rescale (thr=4: P bounded by e^4, exact O/L ratio preserved)
      if (__any(mx > M + 4.f)) {
        const float Mn = fmaxf(M, mx);
        const float al = __expf(M - Mn);
        M = Mn;
        L *= al;
        float alr[16];
#pragma unroll
        for (int c = 0; c < 16; ++c) alr[c] = __shfl(al, (c & 3) + 8 * (c >> 2) + 4 * hi);
#pragma unroll
        for (int dt = 0; dt < 4; ++dt)
#pragma unroll
          for (int c = 0; c < 16; ++c) accO[dt][c] *= alr[c];
      }

      // P = exp(S - M), row sum (1 hop)
      float rs = 0.f;
#pragma unroll
      for (int rt = 0; rt < 2; ++rt)
#pragma unroll
        for (int c = 0; c < 16; ++c) {
          const float pv = __expf(accS[rt][c] - M);
          accS[rt][c] = pv;
          rs += pv;
        }
      rs += __shfl_xor(rs, 32);
      L += rs;

      // pack P pairs (k ascending per word) then half-swap to form PV A-frags:
      // after plswap pairs (0,2),(1,3),(4,6),(5,7): frag(sub) = wv[sub*4 .. +3]
      __builtin_amdgcn_s_setprio(1);
#pragma unroll
      for (int rt = 0; rt < 2; ++rt) {
        uint32_t wv[8];
#pragma unroll
        for (int jj = 0; jj < 8; ++jj)
          wv[jj] = packbf(accS[rt][2 * jj], accS[rt][2 * jj + 1]);
        plswap(wv[0], wv[2]); plswap(wv[1], wv[3]);
        plswap(wv[4], wv[6]); plswap(wv[5], wv[7]);
#pragma unroll
        for (int sub = 0; sub < 2; ++sub) {
          union { uint32_t u[4]; bf16x8 v; } ap;
          ap.u[0] = wv[sub * 4 + 0]; ap.u[1] = wv[sub * 4 + 1];
          ap.u[2] = wv[sub * 4 + 2]; ap.u[3] = wv[sub * 4 + 3];
          const int kbase = rt * 32 + sub * 16 + hi * 8;
#pragma unroll
          for (int dt = 0; dt < 4; ++dt) {
            const int vrow = dt * 32 + lc;
            bf16x8 bv = *(const bf16x8*)(Vb + vrow * 64 + (kbase ^ ((vrow & 7) << 3)));
            accO[dt] = __builtin_amdgcn_mfma_f32_32x32x16_bf16(ap.v, bv, accO[dt], 0, 0, 0);
          }
        }
      }
      __builtin_amdgcn_s_setprio(0);
    }

    asm volatile("s_waitcnt vmcnt(0)" ::: "memory");
    __syncthreads();
  }

  // epilogue: accO[dt]: row q_rel = (c&3)+8*(c>>2)+4*hi, col d = dt*32+lc
  const float ivl = 1.f / L;
  float il[16];
#pragma unroll
  for (int c = 0; c < 16; ++c) il[c] = __shfl(ivl, (c & 3) + 8 * (c >> 2) + 4 * hi);
#pragma unroll
  for (int dt = 0; dt < 4; ++dt)
#pragma unroll
    for (int c = 0; c < 16; ++c) {
      const int p = pmin + (c & 3) + 8 * (c >> 2) + 4 * hi;
      o_r[(size_t)p * E_DIM + h * D_DIM + dt * 32 + lc] = f2bf(accO[dt][c] * il[c]);
    }
}

extern "C" void kernel_launch(void* const* d_in, const int* in_sizes, int n_in,
                              void* d_out, int out_size, void* d_ws, size_t ws_size,
                              hipStream_t stream) {
  const float* x     = (const float*)d_in[0];
  const float* fcos  = (const float*)d_in[1];
  const float* fsin  = (const float*)d_in[2];
  const float* w_in  = (const float*)d_in[3];
  const float* w_out = (const float*)d_in[4];
  float* out = (float*)d_out;

  char* ws = (char*)d_ws;
  size_t off = 0;
  uint16_t* w_inT  = (uint16_t*)(ws + off); off += (size_t)QKV_N * E_DIM * 2;      // 3072x2048 bf16
  uint16_t* w_outT = (uint16_t*)(ws + off); off += (size_t)E_DIM * E_DIM * 2;      // 2048x2048 bf16
  uint16_t* qkv    = (uint16_t*)(ws + off); off += (size_t)S_LEN * QKV_N * 2;      // 4096x3072 bf16
  uint16_t* q_r    = (uint16_t*)(ws + off); off += (size_t)H_NUM * S_LEN * D_DIM * 2;
  uint16_t* k_r    = (uint16_t*)(ws + off); off += (size_t)G_NUM * S_LEN * D_DIM * 2;
  uint16_t* v_t    = (uint16_t*)(ws + off); off += (size_t)G_NUM * D_DIM * S_LEN * 2;
  uint16_t* o_r    = (uint16_t*)(ws + off); off += (size_t)S_LEN * E_DIM * 2;
  // x_bf aliases o_r: x_bf is consumed by gemm1 before attn writes o_r (stream-ordered).
  uint16_t* x_bf   = o_r;  // 4096x2048 bf16, same size as o_r

  // edge conversions: fp32 -> bf16
  conv_f2b<<<(S_LEN * E_DIM) / (256 * 8), 256, 0, stream>>>(x, x_bf);
  transpose_f2b<<<dim3(QKV_N / 64, E_DIM / 64), 256, 0, stream>>>(w_in, w_inT, QKV_N, E_DIM);
  transpose_f2b<<<dim3(E_DIM / 64, E_DIM / 64), 256, 0, stream>>>(w_out, w_outT, E_DIM, E_DIM);
  // qkv = x @ w_in  (bf16 out); grid flattened, %8==0 for XCD swizzle
  gemm_bt<<<(S_LEN / 128) * (QKV_N / 128), 256, 0, stream>>>(x_bf, w_inT, qkv, nullptr,
                                                             S_LEN, QKV_N, E_DIM, S_LEN / 128);
  // rope q,k ; transpose v
  rope_qk<<<(S_LEN * 1280) / 256, 256, 0, stream>>>(qkv, fcos, fsin, q_r, k_r);
  transpose_bf16<<<dim3(512 / 64, S_LEN / 64), 256, 0, stream>>>(qkv + 2560, v_t, QKV_N, S_LEN);
  // attention (QBLK=128, 4 waves x 32 rows, 32x32 MFMA)
  attn_kernel<<<dim3(S_LEN / 128, H_NUM), 256, 0, stream>>>(q_r, k_r, v_t, o_r);
  // out = o @ w_out  (fp32 out)
  gemm_bt<<<(S_LEN / 128) * (E_DIM / 128), 256, 0, stream>>>(o_r, w_outT, nullptr, out,
                                                             S_LEN, E_DIM, E_DIM, S_LEN / 128);
}